// Round 1
// baseline (604.405 us; speedup 1.0000x reference)
//
#include <hip/hip_runtime.h>

#define OUT_W 7
#define OUT_L 7
#define OUT_H 7
#define SR 2
#define CDIM 128
#define WDIM 64
#define LDIM 64
#define HDIM 64

struct ColInfo { int x0, x1, y0, y1; float w00, w10, w01, w11; };
struct ZInfo   { int z0, z1; float hz, lz; };

// One block per (n, c). Threads = output bins (343 active of 384).
// Geometry (xy columns + z taps) computed once per block into LDS.
__global__ __launch_bounds__(384) void roi_align_rot3d_kernel(
    const float* __restrict__ input, const float* __restrict__ rois,
    const float* __restrict__ scale_ptr, float* __restrict__ out)
{
    __shared__ ColInfo cols[OUT_W * SR * OUT_L * SR];  // 196
    __shared__ ZInfo   zs[OUT_H * SR];                 // 14

    const int n = blockIdx.x >> 7;     // / CDIM
    const int c = blockIdx.x & 127;    // % CDIM
    const int t = threadIdx.x;

    const float scale = scale_ptr[0];
    const float* r = rois + (size_t)n * 8;
    const int   b  = (int)r[0];
    const float cx = r[1] * scale, cy = r[2] * scale, cz = r[3] * scale;
    const float sx = r[4] * scale, sy = r[5] * scale, szv = r[6] * scale;
    const float th = r[7];
    const float ct = cosf(th), st = sinf(th);

    if (t < 196) {
        const int isx = t / 14, isy = t - isx * 14;
        const float xx = -0.5f * sx + ((float)isx + 0.5f) * (sx * (1.0f / 14.0f));
        const float yy = -0.5f * sy + ((float)isy + 0.5f) * (sy * (1.0f / 14.0f));
        float x = ct * xx - st * yy + cx;
        float y = st * xx + ct * yy + cy;
        const bool v = (x > -1.0f) && (x < (float)WDIM) && (y > -1.0f) && (y < (float)LDIM);
        x = fminf(fmaxf(x, 0.0f), (float)(WDIM - 1));
        y = fminf(fmaxf(y, 0.0f), (float)(LDIM - 1));
        const int x0 = (int)floorf(x);
        const int y0 = (int)floorf(y);
        const int x1 = min(x0 + 1, WDIM - 1);
        const int y1 = min(y0 + 1, LDIM - 1);
        const float lx = x - (float)x0, ly = y - (float)y0;
        const float hx = 1.0f - lx, hy = 1.0f - ly;
        const float vm = v ? 1.0f : 0.0f;
        cols[t].x0 = x0; cols[t].x1 = x1; cols[t].y0 = y0; cols[t].y1 = y1;
        cols[t].w00 = hx * hy * vm; cols[t].w10 = lx * hy * vm;
        cols[t].w01 = hx * ly * vm; cols[t].w11 = lx * ly * vm;
    } else if (t < 196 + 14) {
        const int s = t - 196;
        const float zraw = -0.5f * szv + ((float)s + 0.5f) * (szv * (1.0f / 14.0f)) + cz;
        const bool v = (zraw > -1.0f) && (zraw < (float)HDIM);
        const float z = fminf(fmaxf(zraw, 0.0f), (float)(HDIM - 1));
        const int z0 = (int)floorf(z);
        const int z1 = min(z0 + 1, HDIM - 1);
        const float lz = z - (float)z0, hz = 1.0f - lz;
        const float vm = v ? 1.0f : 0.0f;
        zs[s].z0 = z0; zs[s].z1 = z1; zs[s].hz = hz * vm; zs[s].lz = lz * vm;
    }
    __syncthreads();

    if (t >= 343) return;
    const int ow = t / 49;
    const int rem = t - ow * 49;
    const int ol = rem / 7;
    const int oh = rem - ol * 7;

    const float* __restrict__ p =
        input + ((size_t)(b * CDIM + c)) * (size_t)(WDIM * LDIM * HDIM);

    float acc = 0.0f;
    #pragma unroll
    for (int dx = 0; dx < 2; ++dx) {
        #pragma unroll
        for (int dy = 0; dy < 2; ++dy) {
            const ColInfo col = cols[(ow * 2 + dx) * 14 + (ol * 2 + dy)];
            const int b00 = col.x0 * (LDIM * HDIM) + col.y0 * HDIM;
            const int b10 = col.x1 * (LDIM * HDIM) + col.y0 * HDIM;
            const int b01 = col.x0 * (LDIM * HDIM) + col.y1 * HDIM;
            const int b11 = col.x1 * (LDIM * HDIM) + col.y1 * HDIM;
            #pragma unroll
            for (int dz = 0; dz < 2; ++dz) {
                const ZInfo zi = zs[oh * 2 + dz];
                const float v00 = zi.hz * p[b00 + zi.z0] + zi.lz * p[b00 + zi.z1];
                const float v10 = zi.hz * p[b10 + zi.z0] + zi.lz * p[b10 + zi.z1];
                const float v01 = zi.hz * p[b01 + zi.z0] + zi.lz * p[b01 + zi.z1];
                const float v11 = zi.hz * p[b11 + zi.z0] + zi.lz * p[b11 + zi.z1];
                acc += col.w00 * v00 + col.w10 * v10 + col.w01 * v01 + col.w11 * v11;
            }
        }
    }
    // out layout: (N, C, OUT_W, OUT_L, OUT_H); t = ow*49 + ol*7 + oh -> coalesced
    out[(size_t)blockIdx.x * 343 + t] = acc * 0.125f;
}

extern "C" void kernel_launch(void* const* d_in, const int* in_sizes, int n_in,
                              void* d_out, int out_size, void* d_ws, size_t ws_size,
                              hipStream_t stream) {
    const float* input = (const float*)d_in[0];
    const float* rois  = (const float*)d_in[1];
    const float* scale = (const float*)d_in[2];
    float* out = (float*)d_out;
    const int N = in_sizes[1] / 8;
    dim3 grid((unsigned)(N * CDIM));
    dim3 block(384);
    hipLaunchKernelGGL(roi_align_rot3d_kernel, grid, block, 0, stream,
                       input, rois, scale, out);
}

// Round 3
// 511.837 us; speedup vs baseline: 1.1809x; 1.1809x over previous
//
#include <hip/hip_runtime.h>

#define OUT_W 7
#define OUT_L 7
#define OUT_H 7
#define SR 2
#define CDIM 128
#define WDIM 64
#define LDIM 64
#define HDIM 64
#define VOLSZ (WDIM * LDIM * HDIM)
#define CPB 2  // channels per block

// b00..b11: flat (x,y) column base offsets for the 4 xy corners of a sample.
struct ColInfo { int b00, b10, b01, b11; float w00, w10, w01, w11; };

// One block per (n, channel-pair). Threads = output bins (343 active of 384).
// Per-bin z work (2 sub-samples x 2 taps) is folded into an 8-tap z filter
// over two aligned float4 loads: all 4 z taps span <=5 voxels (z-step =
// size_z/14 <= 2.29), so [zb4, zb4+7] with zb4 = min(z0_first & ~3, 56)
// always contains them, and zb4 is 16B-aligned within the column.
__global__ __launch_bounds__(384) void roi_align_rot3d_kernel(
    const float* __restrict__ input, const float* __restrict__ rois,
    const float* __restrict__ scale_ptr, float* __restrict__ out)
{
    __shared__ ColInfo cols[OUT_W * SR * OUT_L * SR];   // 196 * 32B
    __shared__ alignas(16) float zw[OUT_H][8];          // 7 x 8 z-weights (per bin)
    __shared__ int zb4s[OUT_H];                         // 7 aligned bases

    const int n = blockIdx.x / (CDIM / CPB);
    const int cp = blockIdx.x - n * (CDIM / CPB);
    const int c0 = cp * CPB;
    const int t = threadIdx.x;

    const float scale = scale_ptr[0];
    const float* r = rois + (size_t)n * 8;
    const int   b  = (int)r[0];
    const float cx = r[1] * scale, cy = r[2] * scale, cz = r[3] * scale;
    const float sx = r[4] * scale, sy = r[5] * scale, szv = r[6] * scale;
    const float th = r[7];
    const float ct = cosf(th), st = sinf(th);

    if (t < 196) {
        const int isx = t / 14, isy = t - isx * 14;
        const float xx = -0.5f * sx + ((float)isx + 0.5f) * (sx * (1.0f / 14.0f));
        const float yy = -0.5f * sy + ((float)isy + 0.5f) * (sy * (1.0f / 14.0f));
        float x = ct * xx - st * yy + cx;
        float y = st * xx + ct * yy + cy;
        const bool v = (x > -1.0f) && (x < (float)WDIM) && (y > -1.0f) && (y < (float)LDIM);
        x = fminf(fmaxf(x, 0.0f), (float)(WDIM - 1));
        y = fminf(fmaxf(y, 0.0f), (float)(LDIM - 1));
        const int x0 = (int)floorf(x);
        const int y0 = (int)floorf(y);
        const int x1 = min(x0 + 1, WDIM - 1);
        const int y1 = min(y0 + 1, LDIM - 1);
        const float lx = x - (float)x0, ly = y - (float)y0;
        const float hx = 1.0f - lx, hy = 1.0f - ly;
        const float vm = v ? 1.0f : 0.0f;
        cols[t].b00 = x0 * (LDIM * HDIM) + y0 * HDIM;
        cols[t].b10 = x1 * (LDIM * HDIM) + y0 * HDIM;
        cols[t].b01 = x0 * (LDIM * HDIM) + y1 * HDIM;
        cols[t].b11 = x1 * (LDIM * HDIM) + y1 * HDIM;
        cols[t].w00 = hx * hy * vm; cols[t].w10 = lx * hy * vm;
        cols[t].w01 = hx * ly * vm; cols[t].w11 = lx * ly * vm;
    } else if (t < 196 + OUT_H) {     // one thread per output z-bin
        const int oh = t - 196;
        float w[8];
        #pragma unroll
        for (int k = 0; k < 8; ++k) w[k] = 0.0f;
        int zb4 = 0;
        #pragma unroll
        for (int dz = 0; dz < 2; ++dz) {
            const int s = oh * 2 + dz;
            const float zraw = -0.5f * szv + ((float)s + 0.5f) * (szv * (1.0f / 14.0f)) + cz;
            const bool v = (zraw > -1.0f) && (zraw < (float)HDIM);
            const float z = fminf(fmaxf(zraw, 0.0f), (float)(HDIM - 1));
            const int z0 = (int)floorf(z);
            const int z1 = min(z0 + 1, HDIM - 1);
            const float lz = z - (float)z0, hz = 1.0f - lz;
            const float vm = v ? 1.0f : 0.0f;
            if (dz == 0) zb4 = min(z0 & ~3, HDIM - 8);
            w[z0 - zb4] += hz * vm;
            w[z1 - zb4] += lz * vm;
        }
        zb4s[oh] = zb4;
        #pragma unroll
        for (int k = 0; k < 8; ++k) zw[oh][k] = w[k];
    }
    __syncthreads();

    if (t >= 343) return;
    const int ow = t / 49;
    const int rem = t - ow * 49;
    const int ol = rem / 7;
    const int oh = rem - ol * 7;

    const float4 zwa = *(const float4*)&zw[oh][0];
    const float4 zwb = *(const float4*)&zw[oh][4];
    const int zb4 = zb4s[oh];

    const float* __restrict__ p =
        input + ((size_t)(b * CDIM + c0)) * (size_t)VOLSZ;

    float acc[CPB];
    #pragma unroll
    for (int cc = 0; cc < CPB; ++cc) acc[cc] = 0.0f;

    #pragma unroll
    for (int dx = 0; dx < 2; ++dx) {
        #pragma unroll
        for (int dy = 0; dy < 2; ++dy) {
            const ColInfo col = cols[(ow * 2 + dx) * 14 + (ol * 2 + dy)];
            const int o00 = col.b00 + zb4;
            const int o10 = col.b10 + zb4;
            const int o01 = col.b01 + zb4;
            const int o11 = col.b11 + zb4;
            #pragma unroll
            for (int cc = 0; cc < CPB; ++cc) {
                const float* __restrict__ pc = p + (size_t)cc * VOLSZ;
                const float4 a00 = *(const float4*)(pc + o00);
                const float4 b00v = *(const float4*)(pc + o00 + 4);
                const float4 a10 = *(const float4*)(pc + o10);
                const float4 b10v = *(const float4*)(pc + o10 + 4);
                const float4 a01 = *(const float4*)(pc + o01);
                const float4 b01v = *(const float4*)(pc + o01 + 4);
                const float4 a11 = *(const float4*)(pc + o11);
                const float4 b11v = *(const float4*)(pc + o11 + 4);
                const float v00 = zwa.x * a00.x + zwa.y * a00.y + zwa.z * a00.z + zwa.w * a00.w
                                + zwb.x * b00v.x + zwb.y * b00v.y + zwb.z * b00v.z + zwb.w * b00v.w;
                const float v10 = zwa.x * a10.x + zwa.y * a10.y + zwa.z * a10.z + zwa.w * a10.w
                                + zwb.x * b10v.x + zwb.y * b10v.y + zwb.z * b10v.z + zwb.w * b10v.w;
                const float v01 = zwa.x * a01.x + zwa.y * a01.y + zwa.z * a01.z + zwa.w * a01.w
                                + zwb.x * b01v.x + zwb.y * b01v.y + zwb.z * b01v.z + zwb.w * b01v.w;
                const float v11 = zwa.x * a11.x + zwa.y * a11.y + zwa.z * a11.z + zwa.w * a11.w
                                + zwb.x * b11v.x + zwb.y * b11v.y + zwb.z * b11v.z + zwb.w * b11v.w;
                acc[cc] += col.w00 * v00 + col.w10 * v10 + col.w01 * v01 + col.w11 * v11;
            }
        }
    }
    #pragma unroll
    for (int cc = 0; cc < CPB; ++cc) {
        out[((size_t)(n * CDIM + c0 + cc)) * 343 + t] = acc[cc] * 0.125f;
    }
}

extern "C" void kernel_launch(void* const* d_in, const int* in_sizes, int n_in,
                              void* d_out, int out_size, void* d_ws, size_t ws_size,
                              hipStream_t stream) {
    const float* input = (const float*)d_in[0];
    const float* rois  = (const float*)d_in[1];
    const float* scale = (const float*)d_in[2];
    float* out = (float*)d_out;
    const int N = in_sizes[1] / 8;
    dim3 grid((unsigned)(N * (CDIM / CPB)));
    dim3 block(384);
    hipLaunchKernelGGL(roi_align_rot3d_kernel, grid, block, 0, stream,
                       input, rois, scale, out);
}